// Round 1
// baseline (589.557 us; speedup 1.0000x reference)
//
#include <hip/hip_runtime.h>

typedef __attribute__((ext_vector_type(8))) __bf16 bf16x8;
typedef __attribute__((ext_vector_type(4))) float f32x4;
typedef unsigned short u16;
typedef unsigned int u32;

__device__ __forceinline__ u16 f2bf(float x) {
  u32 u = __builtin_bit_cast(u32, x);
  u = (u + 0x7FFFu + ((u >> 16) & 1u)) >> 16;
  return (u16)u;
}

// ---------------- fp32 -> bf16 convert (vectorized, 8 elems/thread) ----------
__global__ __launch_bounds__(256) void cvt_f32_bf16(
    const float* __restrict__ in, u16* __restrict__ out, int n8) {
  int i = blockIdx.x * 256 + threadIdx.x;
  if (i >= n8) return;
  const float4* p = reinterpret_cast<const float4*>(in) + (size_t)i * 2;
  float4 a = p[0], b = p[1];
  uint4 r;
  r.x = (u32)f2bf(a.x) | ((u32)f2bf(a.y) << 16);
  r.y = (u32)f2bf(a.z) | ((u32)f2bf(a.w) << 16);
  r.z = (u32)f2bf(b.x) | ((u32)f2bf(b.y) << 16);
  r.w = (u32)f2bf(b.z) | ((u32)f2bf(b.w) << 16);
  reinterpret_cast<uint4*>(out)[i] = r;
}

// ---------------- BT GEMM: C[M,N] = A[M,K] * Bw[N,K]^T  (m97 structure) ------
// MODE 0: scatter epilogue into Qh [B,H,S,64] (pre-scaled 1/8), Kh [B,H,S,64],
//         Vt [B,H,64,S].   MODE 1: fp32 C = acc + bias.
template <int MODE>
__global__ __launch_bounds__(256) void gemm_bt(
    const u16* __restrict__ A, const u16* __restrict__ Bw,
    const float* __restrict__ bias, int N, int K,
    u16* __restrict__ Qh, u16* __restrict__ Kh, u16* __restrict__ Vt,
    float* __restrict__ Cout) {
  __shared__ u16 As[128 * 32];
  __shared__ u16 Bs[128 * 32];
  const int tid = threadIdx.x;
  const int w = tid >> 6, l = tid & 63;
  const int kg = l >> 4, lr = l & 15;
  const int ntn = N >> 7;
  const int tm = blockIdx.x / ntn, tn = blockIdx.x % ntn;
  const int wr = w >> 1, wc = w & 1;

  const u16* Ab = A + (size_t)tm * 128 * K;
  const u16* Bb = Bw + (size_t)tn * 128 * K;

  const f32x4 fz = {0.f, 0.f, 0.f, 0.f};
  f32x4 acc[4][4];
#pragma unroll
  for (int m = 0; m < 4; ++m)
#pragma unroll
    for (int n = 0; n < 4; ++n) acc[m][n] = fz;

  for (int k0 = 0; k0 < K; k0 += 32) {
#pragma unroll
    for (int u = 0; u < 2; ++u) {
      int e = u * 256 + tid;
      const u16* ga = Ab + (size_t)(e >> 2) * K + k0 + (e & 3) * 8;
      const u16* gb = Bb + (size_t)(e >> 2) * K + k0 + (e & 3) * 8;
      __builtin_amdgcn_global_load_lds(
          (const __attribute__((address_space(1))) void*)ga,
          (__attribute__((address_space(3))) void*)(As + (u * 256 + w * 64) * 8),
          16, 0, 0);
      __builtin_amdgcn_global_load_lds(
          (const __attribute__((address_space(1))) void*)gb,
          (__attribute__((address_space(3))) void*)(Bs + (u * 256 + w * 64) * 8),
          16, 0, 0);
    }
    asm volatile("s_waitcnt vmcnt(0)" ::: "memory");
    __syncthreads();
    bf16x8 a[4], b[4];
#pragma unroll
    for (int m = 0; m < 4; ++m)
      a[m] = *(const bf16x8*)(As + (wr * 64 + m * 16 + lr) * 32 + kg * 8);
#pragma unroll
    for (int n = 0; n < 4; ++n)
      b[n] = *(const bf16x8*)(Bs + (wc * 64 + n * 16 + lr) * 32 + kg * 8);
#pragma unroll
    for (int m = 0; m < 4; ++m)
#pragma unroll
      for (int n = 0; n < 4; ++n)
        acc[m][n] =
            __builtin_amdgcn_mfma_f32_16x16x32_bf16(a[m], b[n], acc[m][n], 0, 0, 0);
    __syncthreads();
  }

  // Epilogue. C/D layout: col = lane&15, row = (lane>>4)*4 + j   [m89 verified]
  if (MODE == 0) {
#pragma unroll
    for (int m = 0; m < 4; ++m) {
      const int i0 = tm * 128 + wr * 64 + m * 16 + kg * 4;
#pragma unroll
      for (int n = 0; n < 4; ++n) {
        const int jc = tn * 128 + wc * 64 + n * 16 + lr;
        const float bs = bias[jc];
        const int sel = jc >> 10, h = (jc >> 6) & 15, d = jc & 63;
#pragma unroll
        for (int j = 0; j < 4; ++j) {
          const int i = i0 + j;
          const int b = i >> 11, s = i & 2047;
          const float v = acc[m][n][j] + bs;
          if (sel == 0)
            Qh[((size_t)((b * 16 + h) * 2048 + s)) * 64 + d] = f2bf(v * 0.125f);
          else if (sel == 1)
            Kh[((size_t)((b * 16 + h) * 2048 + s)) * 64 + d] = f2bf(v);
          else
            Vt[((size_t)((b * 16 + h) * 64 + d)) * 2048 + s] = f2bf(v);
        }
      }
    }
  } else {
#pragma unroll
    for (int m = 0; m < 4; ++m) {
      const int i0 = tm * 128 + wr * 64 + m * 16 + kg * 4;
#pragma unroll
      for (int n = 0; n < 4; ++n) {
        const int jc = tn * 128 + wc * 64 + n * 16 + lr;
        const float bs = bias[jc];
#pragma unroll
        for (int j = 0; j < 4; ++j)
          Cout[(size_t)(i0 + j) * N + jc] = acc[m][n][j] + bs;
      }
    }
  }
}

// ---------------- flash attention, LDS-free, permuted-key P-alignment --------
// Qh pre-scaled by 1/sqrt(64). Per wave: 16 q rows. Swapped QK^T: lane (kg,lr)
// holds 16 scores for its own q = qlo+lr. K rows per tile t are loaded in the
// order keymap(t,r) = 32*(t>>1) + 8*(r>>2) + 4*(t&1) + (r&3) so that lane kg
// ends holding exactly keys {8kg..8kg+7} (+32) = the PV A-fragment slots.
__global__ __launch_bounds__(256) void attn_kernel(
    const u16* __restrict__ Qh, const u16* __restrict__ Kh,
    const u16* __restrict__ Vt, u16* __restrict__ Aout) {
  const int tid = threadIdx.x;
  const int w = tid >> 6, l = tid & 63;
  const int kg = l >> 4, lr = l & 15;
  const int bh = blockIdx.x >> 5, qt = blockIdx.x & 31;
  const int qlo = qt * 64 + w * 16;

  const u16* Qb = Qh + ((size_t)(bh * 2048 + qlo + lr)) * 64;
  const bf16x8 aq0 = *(const bf16x8*)(Qb + kg * 8);
  const bf16x8 aq1 = *(const bf16x8*)(Qb + 32 + kg * 8);

  const u16* Kb = Kh + (size_t)bh * 2048 * 64;
  const u16* Vb = Vt + (size_t)bh * 64 * 2048;

  const f32x4 fz = {0.f, 0.f, 0.f, 0.f};
  f32x4 on[4] = {fz, fz, fz, fz};
  float mrun = -1e30f, lrun = 0.f;
  const int krbase = 8 * (lr >> 2) + (lr & 3);

  for (int kc = 0; kc < 2048; kc += 64) {
    f32x4 st[4];
#pragma unroll
    for (int t = 0; t < 4; ++t) {
      const u16* kr =
          Kb + (size_t)(kc + krbase + 4 * (t & 1) + 32 * (t >> 1)) * 64 + kg * 8;
      bf16x8 k0 = *(const bf16x8*)(kr);
      bf16x8 k1 = *(const bf16x8*)(kr + 32);
      f32x4 z = fz;
      z = __builtin_amdgcn_mfma_f32_16x16x32_bf16(k0, aq0, z, 0, 0, 0);
      z = __builtin_amdgcn_mfma_f32_16x16x32_bf16(k1, aq1, z, 0, 0, 0);
      st[t] = z;
    }
    // q-row max: 15 local fmax + cross-kg butterfly
    float rm = st[0][0];
#pragma unroll
    for (int t = 0; t < 4; ++t)
#pragma unroll
      for (int j = 0; j < 4; ++j) rm = fmaxf(rm, st[t][j]);
    rm = fmaxf(rm, __shfl_xor(rm, 16));
    rm = fmaxf(rm, __shfl_xor(rm, 32));
    if (!__all(rm <= mrun + 8.f)) {  // T13 defer-max, THR=8
      float mn = fmaxf(mrun, rm);
      float alpha = __expf(mrun - mn);
      mrun = mn;
      lrun *= alpha;
#pragma unroll
      for (int j = 0; j < 4; ++j) {
        float aj = __shfl(alpha, kg * 4 + j);  // alpha of output-row q=4kg+j
#pragma unroll
        for (int n = 0; n < 4; ++n) on[n][j] *= aj;
      }
    }
    float p[4][4];
    float rs = 0.f;
#pragma unroll
    for (int t = 0; t < 4; ++t)
#pragma unroll
      for (int j = 0; j < 4; ++j) {
        p[t][j] = __expf(st[t][j] - mrun);
        rs += p[t][j];
      }
    rs += __shfl_xor(rs, 16);
    rs += __shfl_xor(rs, 32);
    lrun += rs;
    // P already lane-aligned for the PV A-fragment: ks = t>>1, pos = 4*(t&1)+j
    bf16x8 pa0, pa1;
#pragma unroll
    for (int j = 0; j < 4; ++j) {
      pa0[j] = (__bf16)p[0][j];
      pa0[4 + j] = (__bf16)p[1][j];
      pa1[j] = (__bf16)p[2][j];
      pa1[4 + j] = (__bf16)p[3][j];
    }
#pragma unroll
    for (int n = 0; n < 4; ++n) {
      const u16* vr = Vb + (size_t)(n * 16 + lr) * 2048 + kc + kg * 8;
      bf16x8 v0 = *(const bf16x8*)(vr);
      bf16x8 v1 = *(const bf16x8*)(vr + 32);
      on[n] = __builtin_amdgcn_mfma_f32_16x16x32_bf16(pa0, v0, on[n], 0, 0, 0);
      on[n] = __builtin_amdgcn_mfma_f32_16x16x32_bf16(pa1, v1, on[n], 0, 0, 0);
    }
  }
  // epilogue: output row q = qlo + 4*kg + j, col d = 16n + lr
  const int b = bh >> 4, h = bh & 15;
  u16* Ob = Aout + (size_t)(b * 2048 + qlo + kg * 4) * 1024 + h * 64 + lr;
#pragma unroll
  for (int j = 0; j < 4; ++j) {
    float lj = __shfl(lrun, kg * 4 + j);
    float inv = 1.f / lj;
#pragma unroll
    for (int n = 0; n < 4; ++n) Ob[(size_t)j * 1024 + n * 16] = f2bf(on[n][j] * inv);
  }
}

// ---------------- launch ----------------
extern "C" void kernel_launch(void* const* d_in, const int* in_sizes, int n_in,
                              void* d_out, int out_size, void* d_ws, size_t ws_size,
                              hipStream_t stream) {
  const float* query = (const float*)d_in[0];
  // d_in[1]=key, d_in[2]=value are unused by the reference math
  const float* Wqkv = (const float*)d_in[3];
  const float* bqkv = (const float*)d_in[4];
  const float* Wout = (const float*)d_in[5];
  const float* bout = (const float*)d_in[6];
  float* out = (float*)d_out;

  char* ws = (char*)d_ws;
  u16* qx = (u16*)(ws);                     // 16 MiB: query bf16, reused as attn out
  u16* wqkvb = (u16*)(ws + 16777216);       // 6 MiB
  u16* woutb = (u16*)(ws + 23068672);       // 2 MiB
  u16* Qh = (u16*)(ws + 25165824);          // 16 MiB [B,H,S,64] (pre-scaled)
  u16* Kh = (u16*)(ws + 41943040);          // 16 MiB [B,H,S,64]
  u16* Vt = (u16*)(ws + 58720256);          // 16 MiB [B,H,64,S]
  u16* attn = qx;                           // reuse (qx dead after gemm_qkv)

  cvt_f32_bf16<<<4096, 256, 0, stream>>>(query, qx, 8388608 / 8);
  cvt_f32_bf16<<<1536, 256, 0, stream>>>(Wqkv, wqkvb, 3145728 / 8);
  cvt_f32_bf16<<<512, 256, 0, stream>>>(Wout, woutb, 1048576 / 8);

  gemm_bt<0><<<64 * 24, 256, 0, stream>>>(qx, wqkvb, bqkv, 3072, 1024, Qh, Kh, Vt,
                                          nullptr);
  attn_kernel<<<2048, 256, 0, stream>>>(Qh, Kh, Vt, attn);
  gemm_bt<1><<<64 * 8, 256, 0, stream>>>(attn, woutb, bout, 1024, 1024, nullptr,
                                         nullptr, nullptr, out);
}

// Round 2
// 233.132 us; speedup vs baseline: 2.5289x; 2.5289x over previous
//
#include <hip/hip_runtime.h>

typedef __attribute__((ext_vector_type(8))) __bf16 bf16x8;
typedef __attribute__((ext_vector_type(4))) float f32x4;
typedef unsigned short u16;
typedef unsigned int u32;

__device__ __forceinline__ u16 f2bf(float x) {
  u32 u = __builtin_bit_cast(u32, x);
  u = (u + 0x7FFFu + ((u >> 16) & 1u)) >> 16;
  return (u16)u;
}

// ---------------- fp32 -> bf16 convert (vectorized, 8 elems/thread) ----------
__global__ __launch_bounds__(256) void cvt_f32_bf16(
    const float* __restrict__ in, u16* __restrict__ out, int n8) {
  int i = blockIdx.x * 256 + threadIdx.x;
  if (i >= n8) return;
  const float4* p = reinterpret_cast<const float4*>(in) + (size_t)i * 2;
  float4 a = p[0], b = p[1];
  uint4 r;
  r.x = (u32)f2bf(a.x) | ((u32)f2bf(a.y) << 16);
  r.y = (u32)f2bf(a.z) | ((u32)f2bf(a.w) << 16);
  r.z = (u32)f2bf(b.x) | ((u32)f2bf(b.y) << 16);
  r.w = (u32)f2bf(b.z) | ((u32)f2bf(b.w) << 16);
  reinterpret_cast<uint4*>(out)[i] = r;
}

// ---------------- BT GEMM: C[M,N] = A[M,K] * Bw[N,K]^T  (m97 structure) ------
template <int MODE>
__global__ __launch_bounds__(256) void gemm_bt(
    const u16* __restrict__ A, const u16* __restrict__ Bw,
    const float* __restrict__ bias, int N, int K,
    u16* __restrict__ Qh, u16* __restrict__ Kh, u16* __restrict__ Vt,
    float* __restrict__ Cout) {
  __shared__ u16 As[128 * 32];
  __shared__ u16 Bs[128 * 32];
  const int tid = threadIdx.x;
  const int w = tid >> 6, l = tid & 63;
  const int kg = l >> 4, lr = l & 15;
  const int ntn = N >> 7;
  const int tm = blockIdx.x / ntn, tn = blockIdx.x % ntn;
  const int wr = w >> 1, wc = w & 1;

  const u16* Ab = A + (size_t)tm * 128 * K;
  const u16* Bb = Bw + (size_t)tn * 128 * K;

  const f32x4 fz = {0.f, 0.f, 0.f, 0.f};
  f32x4 acc[4][4];
#pragma unroll
  for (int m = 0; m < 4; ++m)
#pragma unroll
    for (int n = 0; n < 4; ++n) acc[m][n] = fz;

  for (int k0 = 0; k0 < K; k0 += 32) {
#pragma unroll
    for (int u = 0; u < 2; ++u) {
      int e = u * 256 + tid;
      const u16* ga = Ab + (size_t)(e >> 2) * K + k0 + (e & 3) * 8;
      const u16* gb = Bb + (size_t)(e >> 2) * K + k0 + (e & 3) * 8;
      __builtin_amdgcn_global_load_lds(
          (const __attribute__((address_space(1))) void*)ga,
          (__attribute__((address_space(3))) void*)(As + (u * 256 + w * 64) * 8),
          16, 0, 0);
      __builtin_amdgcn_global_load_lds(
          (const __attribute__((address_space(1))) void*)gb,
          (__attribute__((address_space(3))) void*)(Bs + (u * 256 + w * 64) * 8),
          16, 0, 0);
    }
    asm volatile("s_waitcnt vmcnt(0)" ::: "memory");
    __syncthreads();
    bf16x8 a[4], b[4];
#pragma unroll
    for (int m = 0; m < 4; ++m)
      a[m] = *(const bf16x8*)(As + (wr * 64 + m * 16 + lr) * 32 + kg * 8);
#pragma unroll
    for (int n = 0; n < 4; ++n)
      b[n] = *(const bf16x8*)(Bs + (wc * 64 + n * 16 + lr) * 32 + kg * 8);
#pragma unroll
    for (int m = 0; m < 4; ++m)
#pragma unroll
      for (int n = 0; n < 4; ++n)
        acc[m][n] =
            __builtin_amdgcn_mfma_f32_16x16x32_bf16(a[m], b[n], acc[m][n], 0, 0, 0);
    __syncthreads();
  }

  // Epilogue. C/D layout: col = lane&15, row = (lane>>4)*4 + j   [m89 verified]
  if (MODE == 0) {
#pragma unroll
    for (int m = 0; m < 4; ++m) {
      const int i0 = tm * 128 + wr * 64 + m * 16 + kg * 4;
#pragma unroll
      for (int n = 0; n < 4; ++n) {
        const int jc = tn * 128 + wc * 64 + n * 16 + lr;
        const float bs = bias[jc];
        const int sel = jc >> 10, h = (jc >> 6) & 15, d = jc & 63;
#pragma unroll
        for (int j = 0; j < 4; ++j) {
          const int i = i0 + j;
          const int b = i >> 11, s = i & 2047;
          const float v = acc[m][n][j] + bs;
          if (sel == 0)
            Qh[((size_t)((b * 16 + h) * 2048 + s)) * 64 + d] = f2bf(v * 0.125f);
          else if (sel == 1)
            Kh[((size_t)((b * 16 + h) * 2048 + s)) * 64 + d] = f2bf(v);
          else
            Vt[((size_t)((b * 16 + h) * 64 + d)) * 2048 + s] = f2bf(v);
        }
      }
    }
  } else {
#pragma unroll
    for (int m = 0; m < 4; ++m) {
      const int i0 = tm * 128 + wr * 64 + m * 16 + kg * 4;
#pragma unroll
      for (int n = 0; n < 4; ++n) {
        const int jc = tn * 128 + wc * 64 + n * 16 + lr;
        const float bs = bias[jc];
#pragma unroll
        for (int j = 0; j < 4; ++j)
          Cout[(size_t)(i0 + j) * N + jc] = acc[m][n][j] + bs;
      }
    }
  }
}

// ---------------- flash attention: LDS-staged K/V, double-buffered -----------
// 4 waves/block, 32 q-rows/wave (2 x 16-row subtiles), 128 q/block, KVBLK=64.
// K stored at LDS row sigma(key) (swap bits 2<->4) with chunk ^= row&7;
// V stored at row d with chunk ^= d&7. Stage pre-swizzles the GLOBAL source
// (global_load_lds dest must stay linear). Fragment->key mapping identical to
// the verified round-1 math: lane (kg,lq), tile t, reg j holds key
// 32(t>>1)+4(t&1)+8kg+j, which lands at LDS row 32(t>>1)+16(t&1)+8a0+4a1+b.
__global__ __launch_bounds__(256, 4) void attn_kernel(
    const u16* __restrict__ Qh, const u16* __restrict__ Kh,
    const u16* __restrict__ Vt, u16* __restrict__ Aout) {
  __shared__ alignas(16) u16 Kl[2][4096];
  __shared__ alignas(16) u16 Vl[2][4096];
  const int tid = threadIdx.x;
  const int w = tid >> 6, l = tid & 63;
  const int kg = l >> 4, lq = l & 15;
  const int bh = blockIdx.x >> 4, qt = blockIdx.x & 15;
  const int qbase = qt * 128 + w * 32;

  const u16* Qb = Qh + ((size_t)(bh * 2048 + qbase + lq)) * 64;
  const bf16x8 aq00 = *(const bf16x8*)(Qb + kg * 8);
  const bf16x8 aq01 = *(const bf16x8*)(Qb + 32 + kg * 8);
  const bf16x8 aq10 = *(const bf16x8*)(Qb + 16 * 64 + kg * 8);
  const bf16x8 aq11 = *(const bf16x8*)(Qb + 16 * 64 + 32 + kg * 8);

  const u16* Kb = Kh + (size_t)bh * 2048 * 64;
  const u16* Vb = Vt + (size_t)bh * 64 * 2048;

  // fragment-read lane constants
  const int r7K = 4 * (lq >> 3) + (lq & 3);          // sigma-row & 7 (t-invariant)
  const int rowbK = 8 * ((lq >> 2) & 1) + r7K;       // 8*a0 + 4*a1 + b
  const int ckK0 = (kg ^ r7K) * 8;
  const int ckK1 = ((kg + 4) ^ r7K) * 8;
  const int r7V = lq & 7;
  const int ckV0 = (kg ^ r7V) * 8;
  const int ckV1 = ((kg + 4) ^ r7V) * 8;

  const f32x4 fz = {0.f, 0.f, 0.f, 0.f};
  f32x4 on0[4] = {fz, fz, fz, fz};
  f32x4 on1[4] = {fz, fz, fz, fz};
  float m0 = -1e30f, m1 = -1e30f, l0 = 0.f, l1 = 0.f;

  // stage: slot s = (row, chunk c); LDS[row][c] = K[kc + sigma(row)][(c^(row&7))*8..]
#define STAGE_KV(buf, kc)                                                        \
  {                                                                              \
    {                                                                            \
      const int s_ = tid, row_ = s_ >> 3, c_ = s_ & 7;                           \
      const int sw_ = (c_ ^ (row_ & 7)) * 8;                                     \
      const int srow_ = (row_ & ~20) | ((row_ & 4) << 2) | ((row_ & 16) >> 2);   \
      __builtin_amdgcn_global_load_lds(                                          \
          (const __attribute__((address_space(1))) void*)(Kb + (size_t)((kc) + srow_) * 64 + sw_), \
          (__attribute__((address_space(3))) void*)(&Kl[buf][s_ * 8]), 16, 0, 0);\
      __builtin_amdgcn_global_load_lds(                                          \
          (const __attribute__((address_space(1))) void*)(Vb + (size_t)row_ * 2048 + (kc) + sw_),  \
          (__attribute__((address_space(3))) void*)(&Vl[buf][s_ * 8]), 16, 0, 0);\
    }                                                                            \
    {                                                                            \
      const int s_ = 256 + tid, row_ = s_ >> 3, c_ = s_ & 7;                     \
      const int sw_ = (c_ ^ (row_ & 7)) * 8;                                     \
      const int srow_ = (row_ & ~20) | ((row_ & 4) << 2) | ((row_ & 16) >> 2);   \
      __builtin_amdgcn_global_load_lds(                                          \
          (const __attribute__((address_space(1))) void*)(Kb + (size_t)((kc) + srow_) * 64 + sw_), \
          (__attribute__((address_space(3))) void*)(&Kl[buf][s_ * 8]), 16, 0, 0);\
      __builtin_amdgcn_global_load_lds(                                          \
          (const __attribute__((address_space(1))) void*)(Vb + (size_t)row_ * 2048 + (kc) + sw_),  \
          (__attribute__((address_space(3))) void*)(&Vl[buf][s_ * 8]), 16, 0, 0);\
    }                                                                            \
  }

  STAGE_KV(0, 0);
  asm volatile("s_waitcnt vmcnt(0)" ::: "memory");
  __syncthreads();

  int cur = 0;
  for (int kc = 0; kc < 2048; kc += 64) {
    if (kc + 64 < 2048) STAGE_KV(cur ^ 1, kc + 64);
    const u16* Klc = Kl[cur];
    const u16* Vlc = Vl[cur];

    f32x4 st0[4], st1[4];
#pragma unroll
    for (int t = 0; t < 4; ++t) {
      const int ro = (rowbK + ((t >> 1) * 32 + (t & 1) * 16)) * 64;
      bf16x8 k0 = *(const bf16x8*)(Klc + ro + ckK0);
      bf16x8 k1 = *(const bf16x8*)(Klc + ro + ckK1);
      f32x4 z0 = fz, z1 = fz;
      z0 = __builtin_amdgcn_mfma_f32_16x16x32_bf16(k0, aq00, z0, 0, 0, 0);
      z0 = __builtin_amdgcn_mfma_f32_16x16x32_bf16(k1, aq01, z0, 0, 0, 0);
      z1 = __builtin_amdgcn_mfma_f32_16x16x32_bf16(k0, aq10, z1, 0, 0, 0);
      z1 = __builtin_amdgcn_mfma_f32_16x16x32_bf16(k1, aq11, z1, 0, 0, 0);
      st0[t] = z0;
      st1[t] = z1;
    }

    float rm0 = st0[0][0], rm1 = st1[0][0];
#pragma unroll
    for (int t = 0; t < 4; ++t)
#pragma unroll
      for (int j = 0; j < 4; ++j) {
        rm0 = fmaxf(rm0, st0[t][j]);
        rm1 = fmaxf(rm1, st1[t][j]);
      }
    rm0 = fmaxf(rm0, __shfl_xor(rm0, 16));
    rm0 = fmaxf(rm0, __shfl_xor(rm0, 32));
    rm1 = fmaxf(rm1, __shfl_xor(rm1, 16));
    rm1 = fmaxf(rm1, __shfl_xor(rm1, 32));
    if (!__all(fmaxf(rm0 - m0, rm1 - m1) <= 8.f)) {  // T13 defer-max
      float mn0 = fmaxf(m0, rm0), mn1 = fmaxf(m1, rm1);
      float a0 = __expf(m0 - mn0), a1 = __expf(m1 - mn1);
      m0 = mn0;
      m1 = mn1;
      l0 *= a0;
      l1 *= a1;
#pragma unroll
      for (int j = 0; j < 4; ++j) {
        float aj0 = __shfl(a0, kg * 4 + j);
        float aj1 = __shfl(a1, kg * 4 + j);
#pragma unroll
        for (int n = 0; n < 4; ++n) {
          on0[n][j] *= aj0;
          on1[n][j] *= aj1;
        }
      }
    }

    bf16x8 pa00, pa01, pa10, pa11;
    {
      float rs = 0.f;
      float p[4][4];
#pragma unroll
      for (int t = 0; t < 4; ++t)
#pragma unroll
        for (int j = 0; j < 4; ++j) {
          p[t][j] = __expf(st0[t][j] - m0);
          rs += p[t][j];
        }
      rs += __shfl_xor(rs, 16);
      rs += __shfl_xor(rs, 32);
      l0 += rs;
#pragma unroll
      for (int j = 0; j < 4; ++j) {
        pa00[j] = (__bf16)p[0][j];
        pa00[4 + j] = (__bf16)p[1][j];
        pa01[j] = (__bf16)p[2][j];
        pa01[4 + j] = (__bf16)p[3][j];
      }
    }
    {
      float rs = 0.f;
      float p[4][4];
#pragma unroll
      for (int t = 0; t < 4; ++t)
#pragma unroll
        for (int j = 0; j < 4; ++j) {
          p[t][j] = __expf(st1[t][j] - m1);
          rs += p[t][j];
        }
      rs += __shfl_xor(rs, 16);
      rs += __shfl_xor(rs, 32);
      l1 += rs;
#pragma unroll
      for (int j = 0; j < 4; ++j) {
        pa10[j] = (__bf16)p[0][j];
        pa10[4 + j] = (__bf16)p[1][j];
        pa11[j] = (__bf16)p[2][j];
        pa11[4 + j] = (__bf16)p[3][j];
      }
    }

#pragma unroll
    for (int n = 0; n < 4; ++n) {
      const int ro = (n * 16 + lq) * 64;
      bf16x8 v0 = *(const bf16x8*)(Vlc + ro + ckV0);
      bf16x8 v1 = *(const bf16x8*)(Vlc + ro + ckV1);
      on0[n] = __builtin_amdgcn_mfma_f32_16x16x32_bf16(pa00, v0, on0[n], 0, 0, 0);
      on0[n] = __builtin_amdgcn_mfma_f32_16x16x32_bf16(pa01, v1, on0[n], 0, 0, 0);
      on1[n] = __builtin_amdgcn_mfma_f32_16x16x32_bf16(pa10, v0, on1[n], 0, 0, 0);
      on1[n] = __builtin_amdgcn_mfma_f32_16x16x32_bf16(pa11, v1, on1[n], 0, 0, 0);
    }

    asm volatile("s_waitcnt vmcnt(0)" ::: "memory");
    __syncthreads();
    cur ^= 1;
  }

  // epilogue: output row q = qbase + s*16 + 4*kg + j, col d = 16n + lq
  const int b = bh >> 4, h = bh & 15;
  {
    u16* Ob = Aout + (size_t)(b * 2048 + qbase + kg * 4) * 1024 + h * 64 + lq;
#pragma unroll
    for (int j = 0; j < 4; ++j) {
      float lj = __shfl(l0, kg * 4 + j);
      float inv = 1.f / lj;
#pragma unroll
      for (int n = 0; n < 4; ++n)
        Ob[(size_t)j * 1024 + n * 16] = f2bf(on0[n][j] * inv);
    }
  }
  {
    u16* Ob = Aout + (size_t)(b * 2048 + qbase + 16 + kg * 4) * 1024 + h * 64 + lq;
#pragma unroll
    for (int j = 0; j < 4; ++j) {
      float lj = __shfl(l1, kg * 4 + j);
      float inv = 1.f / lj;
#pragma unroll
      for (int n = 0; n < 4; ++n)
        Ob[(size_t)j * 1024 + n * 16] = f2bf(on1[n][j] * inv);
    }
  }
}

// ---------------- launch ----------------
extern "C" void kernel_launch(void* const* d_in, const int* in_sizes, int n_in,
                              void* d_out, int out_size, void* d_ws, size_t ws_size,
                              hipStream_t stream) {
  const float* query = (const float*)d_in[0];
  const float* Wqkv = (const float*)d_in[3];
  const float* bqkv = (const float*)d_in[4];
  const float* Wout = (const float*)d_in[5];
  const float* bout = (const float*)d_in[6];
  float* out = (float*)d_out;

  char* ws = (char*)d_ws;
  u16* qx = (u16*)(ws);                     // 16 MiB: query bf16, reused as attn out
  u16* wqkvb = (u16*)(ws + 16777216);       // 6 MiB
  u16* woutb = (u16*)(ws + 23068672);       // 2 MiB
  u16* Qh = (u16*)(ws + 25165824);          // 16 MiB [B,H,S,64] (pre-scaled)
  u16* Kh = (u16*)(ws + 41943040);          // 16 MiB [B,H,S,64]
  u16* Vt = (u16*)(ws + 58720256);          // 16 MiB [B,H,64,S]
  u16* attn = qx;                           // reuse (qx dead after gemm_qkv)

  cvt_f32_bf16<<<4096, 256, 0, stream>>>(query, qx, 8388608 / 8);
  cvt_f32_bf16<<<1536, 256, 0, stream>>>(Wqkv, wqkvb, 3145728 / 8);
  cvt_f32_bf16<<<512, 256, 0, stream>>>(Wout, woutb, 1048576 / 8);

  gemm_bt<0><<<64 * 24, 256, 0, stream>>>(qx, wqkvb, bqkv, 3072, 1024, Qh, Kh, Vt,
                                          nullptr);
  attn_kernel<<<1024, 256, 0, stream>>>(Qh, Kh, Vt, attn);
  gemm_bt<1><<<64 * 8, 256, 0, stream>>>(attn, woutb, bout, 1024, 1024, nullptr,
                                         nullptr, nullptr, out);
}

// Round 3
// 211.403 us; speedup vs baseline: 2.7888x; 1.1028x over previous
//
#include <hip/hip_runtime.h>

typedef __attribute__((ext_vector_type(8))) __bf16 bf16x8;
typedef __attribute__((ext_vector_type(4))) float f32x4;
typedef unsigned short u16;
typedef unsigned int u32;

__device__ __forceinline__ u16 f2bf(float x) {
  u32 u = __builtin_bit_cast(u32, x);
  u = (u + 0x7FFFu + ((u >> 16) & 1u)) >> 16;
  return (u16)u;
}

#define BAR()                          \
  {                                    \
    asm volatile("" ::: "memory");     \
    __builtin_amdgcn_s_barrier();      \
    asm volatile("" ::: "memory");     \
  }

// ---------------- fp32 -> bf16 convert (vectorized, 8 elems/thread) ----------
__global__ __launch_bounds__(256) void cvt_f32_bf16(
    const float* __restrict__ in, u16* __restrict__ out, int n8) {
  int i = blockIdx.x * 256 + threadIdx.x;
  if (i >= n8) return;
  const float4* p = reinterpret_cast<const float4*>(in) + (size_t)i * 2;
  float4 a = p[0], b = p[1];
  uint4 r;
  r.x = (u32)f2bf(a.x) | ((u32)f2bf(a.y) << 16);
  r.y = (u32)f2bf(a.z) | ((u32)f2bf(a.w) << 16);
  r.z = (u32)f2bf(b.x) | ((u32)f2bf(b.y) << 16);
  r.w = (u32)f2bf(b.z) | ((u32)f2bf(b.w) << 16);
  reinterpret_cast<uint4*>(out)[i] = r;
}

// ============ QKV GEMM: 256x256 tile, BK=64, 8-phase counted-vmcnt ==========
// C[8192,3072] = A[8192,1024] * Bw[3072,1024]^T, scatter epilogue to Q/K/V.
// 8 waves (2Mx4N), per-wave out 128x64 (m-frags 8, n-frags 4, interleaved at
// 16-row/col granularity). Halves = 128-row blocks of A/B tiles (16 KB each).
// LDS chunk swizzle: 16B chunk c of row r holds logical chunk c^(r&7)
// (R2-verified conflict-free). Counted vmcnt(4) once per K-tile.
__global__ __launch_bounds__(512, 2) void gemm_qkv8(
    const u16* __restrict__ A, const u16* __restrict__ Bw,
    const float* __restrict__ bias, u16* __restrict__ Qh,
    u16* __restrict__ Kh, u16* __restrict__ Vt) {
  constexpr int K = 1024;
  constexpr int NT = 16;  // K / 64
  __shared__ u16 Als[2][2][128][64];
  __shared__ u16 Bls[2][2][128][64];
  u16* const ALp = &Als[0][0][0][0];
  u16* const BLp = &Bls[0][0][0][0];

  const int tid = threadIdx.x;
  const int w = tid >> 6, l = tid & 63;
  const int kg = l >> 4, lr = l & 15;
  const int wr = w >> 2, wc = w & 3;
  // XCD-aware swizzle (384 % 8 == 0 -> simple form bijective)
  const int bid = blockIdx.x;
  const int wg = (bid & 7) * 48 + (bid >> 3);
  const int tm = wg / 12, tn = wg % 12;

  // staging constants: slot0 = tid, slot1 = tid+512 (row+64, same chunk perm)
  const int r0 = tid >> 3, c0 = tid & 7;
  const int lc0 = c0 ^ (r0 & 7);
  const int ldsOff0 = tid * 8, ldsOff1 = tid * 8 + 4096;
  const u16* aSrc0[2];
  const u16* bSrc0[2];
#pragma unroll
  for (int h = 0; h < 2; ++h) {
    aSrc0[h] = A + (size_t)(tm * 256 + h * 128 + r0) * K + lc0 * 8;
    bSrc0[h] = Bw + (size_t)(tn * 256 + h * 128 + r0) * K + lc0 * 8;
  }
  const size_t rowStep = (size_t)64 * K;  // +64 rows for slot1

#define ISSUE_A(BUF, H, T)                                                      \
  {                                                                             \
    __builtin_amdgcn_global_load_lds(                                           \
        (const __attribute__((address_space(1))) void*)(aSrc0[H] + (T) * 64),   \
        (__attribute__((address_space(3))) void*)(ALp + (BUF) * 16384 +         \
                                                 (H) * 8192 + ldsOff0),         \
        16, 0, 0);                                                              \
    __builtin_amdgcn_global_load_lds(                                           \
        (const __attribute__((address_space(1))) void*)(aSrc0[H] + rowStep +    \
                                                        (T) * 64),              \
        (__attribute__((address_space(3))) void*)(ALp + (BUF) * 16384 +         \
                                                 (H) * 8192 + ldsOff1),         \
        16, 0, 0);                                                              \
  }
#define ISSUE_B(BUF, H, T)                                                      \
  {                                                                             \
    __builtin_amdgcn_global_load_lds(                                           \
        (const __attribute__((address_space(1))) void*)(bSrc0[H] + (T) * 64),   \
        (__attribute__((address_space(3))) void*)(BLp + (BUF) * 16384 +         \
                                                 (H) * 8192 + ldsOff0),         \
        16, 0, 0);                                                              \
    __builtin_amdgcn_global_load_lds(                                           \
        (const __attribute__((address_space(1))) void*)(bSrc0[H] + rowStep +    \
                                                        (T) * 64),              \
        (__attribute__((address_space(3))) void*)(BLp + (BUF) * 16384 +         \
                                                 (H) * 8192 + ldsOff1),         \
        16, 0, 0);                                                              \
  }

  // fragment-read constants
  const int x7 = lr & 7;
  const int pc0 = (kg ^ x7) * 8;
  const int pc1 = ((kg + 4) ^ x7) * 8;
  const int wr16lr = wr * 16 + lr;
  const int wc16lr = wc * 16 + lr;

  const f32x4 fz = {0.f, 0.f, 0.f, 0.f};
  f32x4 acc[8][4];
#pragma unroll
  for (int m = 0; m < 8; ++m)
#pragma unroll
    for (int n = 0; n < 4; ++n) acc[m][n] = fz;

  bf16x8 aF[4][2], bF[2][2];

#define READ_A(P, MH)                                                           \
  {                                                                             \
    const u16* bp = ALp + (P) * 16384 + (MH) * 8192;                            \
    _Pragma("unroll") for (int mi = 0; mi < 4; ++mi) {                          \
      const u16* rp = bp + (mi * 32 + wr16lr) * 64;                             \
      aF[mi][0] = *(const bf16x8*)(rp + pc0);                                   \
      aF[mi][1] = *(const bf16x8*)(rp + pc1);                                   \
    }                                                                           \
  }
#define READ_B(P, NH)                                                           \
  {                                                                             \
    const u16* bp = BLp + (P) * 16384 + (NH) * 8192;                            \
    _Pragma("unroll") for (int ni = 0; ni < 2; ++ni) {                          \
      const u16* rp = bp + (ni * 64 + wc16lr) * 64;                             \
      bF[ni][0] = *(const bf16x8*)(rp + pc0);                                   \
      bF[ni][1] = *(const bf16x8*)(rp + pc1);                                   \
    }                                                                           \
  }
#define MFMA_Q(MH, NH)                                                          \
  {                                                                             \
    _Pragma("unroll") for (int mi = 0; mi < 4; ++mi)                            \
        _Pragma("unroll") for (int ni = 0; ni < 2; ++ni) {                      \
      acc[(MH)*4 + mi][(NH)*2 + ni] = __builtin_amdgcn_mfma_f32_16x16x32_bf16(  \
          aF[mi][0], bF[ni][0], acc[(MH)*4 + mi][(NH)*2 + ni], 0, 0, 0);        \
      acc[(MH)*4 + mi][(NH)*2 + ni] = __builtin_amdgcn_mfma_f32_16x16x32_bf16(  \
          aF[mi][1], bF[ni][1], acc[(MH)*4 + mi][(NH)*2 + ni], 0, 0, 0);        \
    }                                                                           \
  }

  // prologue: tile0 all 4 halves, then A-lo(1), B-hi(1) (last 4 loads = slack)
  ISSUE_A(0, 0, 0);
  ISSUE_A(0, 1, 0);
  ISSUE_B(0, 0, 0);
  ISSUE_B(0, 1, 0);
  ISSUE_A(1, 0, 1);
  ISSUE_B(1, 1, 1);

  for (int t = 0; t < NT; ++t) {
    const int p = t & 1;
    if (t == NT - 1) {
      asm volatile("s_waitcnt vmcnt(0)" ::: "memory");
    } else {
      asm volatile("s_waitcnt vmcnt(4)" ::: "memory");
    }
    BAR();
    // ph0: (mh0, nh0)
    if (t + 1 < NT) ISSUE_B(p ^ 1, 0, t + 1);
    READ_A(p, 0);
    READ_B(p, 0);
    BAR();
    __builtin_amdgcn_s_setprio(1);
    MFMA_Q(0, 0);
    __builtin_amdgcn_s_setprio(0);
    BAR();
    // ph1: (mh0, nh1)
    if (t + 1 < NT) ISSUE_A(p ^ 1, 1, t + 1);
    READ_B(p, 1);
    BAR();
    __builtin_amdgcn_s_setprio(1);
    MFMA_Q(0, 1);
    __builtin_amdgcn_s_setprio(0);
    BAR();
    // ph2: (mh1, nh1)
    if (t + 2 < NT) ISSUE_A(p, 0, t + 2);
    READ_A(p, 1);
    BAR();
    __builtin_amdgcn_s_setprio(1);
    MFMA_Q(1, 1);
    __builtin_amdgcn_s_setprio(0);
    BAR();
    // ph3: (mh1, nh0)
    if (t + 2 < NT) ISSUE_B(p, 1, t + 2);
    READ_B(p, 0);
    BAR();
    __builtin_amdgcn_s_setprio(1);
    MFMA_Q(1, 0);
    __builtin_amdgcn_s_setprio(0);
    BAR();
  }

  // epilogue: C row i = tm*256 + m*32 + wr*16 + kg*4 + j; col = tn*256 + n*64
  // + wc*16 + lr.  Q pre-scaled by 0.125*log2(e) for exp2 softmax.
#pragma unroll
  for (int m = 0; m < 8; ++m) {
    const int i0 = tm * 256 + m * 32 + wr * 16 + kg * 4;
    const int b = i0 >> 11, s0 = i0 & 2047;
#pragma unroll
    for (int n = 0; n < 4; ++n) {
      const int jc = tn * 256 + n * 64 + wc * 16 + lr;
      const float bs = bias[jc];
      const int sel = jc >> 10, hh = (jc >> 6) & 15, d = jc & 63;
      if (sel == 0) {
        u16* qp = Qh + ((size_t)((b * 16 + hh) * 2048 + s0)) * 64 + d;
#pragma unroll
        for (int j = 0; j < 4; ++j)
          qp[(size_t)j * 64] = f2bf((acc[m][n][j] + bs) * 0.18033688f);
      } else if (sel == 1) {
        u16* kp = Kh + ((size_t)((b * 16 + hh) * 2048 + s0)) * 64 + d;
#pragma unroll
        for (int j = 0; j < 4; ++j) kp[(size_t)j * 64] = f2bf(acc[m][n][j] + bs);
      } else {
        ushort4 vv;
        vv.x = f2bf(acc[m][n][0] + bs);
        vv.y = f2bf(acc[m][n][1] + bs);
        vv.z = f2bf(acc[m][n][2] + bs);
        vv.w = f2bf(acc[m][n][3] + bs);
        *(ushort4*)(Vt + ((size_t)((b * 16 + hh) * 64 + d)) * 2048 + s0) = vv;
      }
    }
  }
#undef ISSUE_A
#undef ISSUE_B
#undef READ_A
#undef READ_B
#undef MFMA_Q
}

// ---------------- out-proj GEMM: 128^2 m97 structure (verified) --------------
__global__ __launch_bounds__(256) void gemm_out_k(
    const u16* __restrict__ A, const u16* __restrict__ Bw,
    const float* __restrict__ bias, float* __restrict__ Cout) {
  constexpr int N = 1024, K = 1024;
  __shared__ u16 As[128 * 32];
  __shared__ u16 Bs[128 * 32];
  const int tid = threadIdx.x;
  const int w = tid >> 6, l = tid & 63;
  const int kg = l >> 4, lr = l & 15;
  const int bid = blockIdx.x;
  const int wg = (bid & 7) * 64 + (bid >> 3);  // 512 blocks, XCD swizzle
  const int tm = wg >> 3, tn = wg & 7;
  const int wr = w >> 1, wc = w & 1;

  const u16* Ab = A + (size_t)tm * 128 * K;
  const u16* Bb = Bw + (size_t)tn * 128 * K;

  const f32x4 fz = {0.f, 0.f, 0.f, 0.f};
  f32x4 acc[4][4];
#pragma unroll
  for (int m = 0; m < 4; ++m)
#pragma unroll
    for (int n = 0; n < 4; ++n) acc[m][n] = fz;

  for (int k0 = 0; k0 < K; k0 += 32) {
#pragma unroll
    for (int u = 0; u < 2; ++u) {
      int e = u * 256 + tid;
      const u16* ga = Ab + (size_t)(e >> 2) * K + k0 + (e & 3) * 8;
      const u16* gb = Bb + (size_t)(e >> 2) * K + k0 + (e & 3) * 8;
      __builtin_amdgcn_global_load_lds(
          (const __attribute__((address_space(1))) void*)ga,
          (__attribute__((address_space(3))) void*)(As + (u * 256 + w * 64) * 8),
          16, 0, 0);
      __builtin_amdgcn_global_load_lds(
          (const __attribute__((address_space(1))) void*)gb,
          (__attribute__((address_space(3))) void*)(Bs + (u * 256 + w * 64) * 8),
          16, 0, 0);
    }
    asm volatile("s_waitcnt vmcnt(0)" ::: "memory");
    __syncthreads();
    bf16x8 a[4], b[4];
#pragma unroll
    for (int m = 0; m < 4; ++m)
      a[m] = *(const bf16x8*)(As + (wr * 64 + m * 16 + lr) * 32 + kg * 8);
#pragma unroll
    for (int n = 0; n < 4; ++n)
      b[n] = *(const bf16x8*)(Bs + (wc * 64 + n * 16 + lr) * 32 + kg * 8);
#pragma unroll
    for (int m = 0; m < 4; ++m)
#pragma unroll
      for (int n = 0; n < 4; ++n)
        acc[m][n] =
            __builtin_amdgcn_mfma_f32_16x16x32_bf16(a[m], b[n], acc[m][n], 0, 0, 0);
    __syncthreads();
  }

#pragma unroll
  for (int m = 0; m < 4; ++m) {
    const int i0 = tm * 128 + wr * 64 + m * 16 + kg * 4;
#pragma unroll
    for (int n = 0; n < 4; ++n) {
      const int jc = tn * 128 + wc * 64 + n * 16 + lr;
      const float bs = bias[jc];
#pragma unroll
      for (int j = 0; j < 4; ++j)
        Cout[(size_t)(i0 + j) * N + jc] = acc[m][n][j] + bs;
    }
  }
}

// ---------------- flash attention: LDS-staged K/V, double-buffered -----------
// Scores arrive pre-scaled by log2(e)/8 -> softmax in base-2 (v_exp_f32 direct)
__global__ __launch_bounds__(256, 4) void attn_kernel(
    const u16* __restrict__ Qh, const u16* __restrict__ Kh,
    const u16* __restrict__ Vt, u16* __restrict__ Aout) {
  __shared__ alignas(16) u16 Kl[2][4096];
  __shared__ alignas(16) u16 Vl[2][4096];
  const int tid = threadIdx.x;
  const int w = tid >> 6, l = tid & 63;
  const int kg = l >> 4, lq = l & 15;
  const int bid = blockIdx.x;
  const int wgi = (bid & 7) * 128 + (bid >> 3);  // XCD swizzle (1024 % 8 == 0)
  const int bh = wgi >> 4, qt = wgi & 15;
  const int qbase = qt * 128 + w * 32;

  const u16* Qb = Qh + ((size_t)(bh * 2048 + qbase + lq)) * 64;
  const bf16x8 aq00 = *(const bf16x8*)(Qb + kg * 8);
  const bf16x8 aq01 = *(const bf16x8*)(Qb + 32 + kg * 8);
  const bf16x8 aq10 = *(const bf16x8*)(Qb + 16 * 64 + kg * 8);
  const bf16x8 aq11 = *(const bf16x8*)(Qb + 16 * 64 + 32 + kg * 8);

  const u16* Kb = Kh + (size_t)bh * 2048 * 64;
  const u16* Vb = Vt + (size_t)bh * 64 * 2048;

  const int r7K = 4 * (lq >> 3) + (lq & 3);
  const int rowbK = 8 * ((lq >> 2) & 1) + r7K;
  const int ckK0 = (kg ^ r7K) * 8;
  const int ckK1 = ((kg + 4) ^ r7K) * 8;
  const int r7V = lq & 7;
  const int ckV0 = (kg ^ r7V) * 8;
  const int ckV1 = ((kg + 4) ^ r7V) * 8;

  const f32x4 fz = {0.f, 0.f, 0.f, 0.f};
  f32x4 on0[4] = {fz, fz, fz, fz};
  f32x4 on1[4] = {fz, fz, fz, fz};
  float m0 = -1e30f, m1 = -1e30f, l0 = 0.f, l1 = 0.f;

#define STAGE_KV(buf, kc)                                                        \
  {                                                                              \
    {                                                                            \
      const int s_ = tid, row_ = s_ >> 3, c_ = s_ & 7;                           \
      const int sw_ = (c_ ^ (row_ & 7)) * 8;                                     \
      const int srow_ = (row_ & ~20) | ((row_ & 4) << 2) | ((row_ & 16) >> 2);   \
      __builtin_amdgcn_global_load_lds(                                          \
          (const __attribute__((address_space(1))) void*)(Kb + (size_t)((kc) + srow_) * 64 + sw_), \
          (__attribute__((address_space(3))) void*)(&Kl[buf][s_ * 8]), 16, 0, 0);\
      __builtin_amdgcn_global_load_lds(                                          \
          (const __attribute__((address_space(1))) void*)(Vb + (size_t)row_ * 2048 + (kc) + sw_),  \
          (__attribute__((address_space(3))) void*)(&Vl[buf][s_ * 8]), 16, 0, 0);\
    }                                                                            \
    {                                                                            \
      const int s_ = 256 + tid, row_ = s_ >> 3, c_ = s_ & 7;                     \
      const int sw_ = (c_ ^ (row_ & 7)) * 8;                                     \
      const int srow_ = (row_ & ~20) | ((row_ & 4) << 2) | ((row_ & 16) >> 2);   \
      __builtin_amdgcn_global_load_lds(                                          \
          (const __attribute__((address_space(1))) void*)(Kb + (size_t)((kc) + srow_) * 64 + sw_), \
          (__attribute__((address_space(3))) void*)(&Kl[buf][s_ * 8]), 16, 0, 0);\
      __builtin_amdgcn_global_load_lds(                                          \
          (const __attribute__((address_space(1))) void*)(Vb + (size_t)row_ * 2048 + (kc) + sw_),  \
          (__attribute__((address_space(3))) void*)(&Vl[buf][s_ * 8]), 16, 0, 0);\
    }                                                                            \
  }

  STAGE_KV(0, 0);
  asm volatile("s_waitcnt vmcnt(0)" ::: "memory");
  __syncthreads();

  int cur = 0;
  for (int kc = 0; kc < 2048; kc += 64) {
    if (kc + 64 < 2048) STAGE_KV(cur ^ 1, kc + 64);
    const u16* Klc = Kl[cur];
    const u16* Vlc = Vl[cur];

    f32x4 st0[4], st1[4];
    __builtin_amdgcn_s_setprio(1);
#pragma unroll
    for (int t = 0; t < 4; ++t) {
      const int ro = (rowbK + ((t >> 1) * 32 + (t & 1) * 16)) * 64;
      bf16x8 k0 = *(const bf16x8*)(Klc + ro + ckK0);
      bf16x8 k1 = *(const bf16x8*)(Klc + ro + ckK1);
      f32x4 z0 = fz, z1 = fz;
      z0 = __builtin_amdgcn_mfma_f32_16x16x32_bf16(k0, aq00, z0, 0, 0, 0);
      z0 = __builtin_amdgcn_mfma_f32_16x16x32_bf16(k1, aq01, z0, 0, 0, 0);
      z1 = __builtin_amdgcn_mfma_f32_16x16x32_bf16(k0, aq10, z1, 0, 0, 0);
      z1 = __builtin_amdgcn_mfma_f32_16x16x32_bf16(k1, aq11, z1, 0, 0, 0);
      st0[t] = z0;
      st1[t] = z1;
    }
    __builtin_amdgcn_s_setprio(0);

    float rm0 = st0[0][0], rm1 = st1[0][0];
#pragma unroll
    for (int t = 0; t < 4; ++t)
#pragma unroll
      for (int j = 0; j < 4; ++j) {
        rm0 = fmaxf(rm0, st0[t][j]);
        rm1 = fmaxf(rm1, st1[t][j]);
      }
    rm0 = fmaxf(rm0, __shfl_xor(rm0, 16));
    rm0 = fmaxf(rm0, __shfl_xor(rm0, 32));
    rm1 = fmaxf(rm1, __shfl_xor(rm1, 16));
    rm1 = fmaxf(rm1, __shfl_xor(rm1, 32));
    if (!__all(fmaxf(rm0 - m0, rm1 - m1) <= 8.f)) {  // T13 defer-max (base-2)
      float mn0 = fmaxf(m0, rm0), mn1 = fmaxf(m1, rm1);
      float a0 = __builtin_amdgcn_exp2f(m0 - mn0);
      float a1 = __builtin_amdgcn_exp2f(m1 - mn1);
      m0 = mn0;
      m1 = mn1;
      l0 *= a0;
      l1 *= a1;
#pragma unroll
      for (int j = 0; j < 4; ++j) {
        float aj0 = __shfl(a0, kg * 4 + j);
        float aj1 = __shfl(a1, kg * 4 + j);
#pragma unroll
        for (int n = 0; n < 4; ++n) {
          on0[n][j] *= aj0;
          on1[n][j] *= aj1;
        }
      }
    }

    bf16x8 pa00, pa01, pa10, pa11;
    {
      float rs = 0.f;
      float p[4][4];
#pragma unroll
      for (int t = 0; t < 4; ++t)
#pragma unroll
        for (int j = 0; j < 4; ++j) {
          p[t][j] = __builtin_amdgcn_exp2f(st0[t][j] - m0);
          rs += p[t][j];
        }
      rs += __shfl_xor(rs, 16);
      rs += __shfl_xor(rs, 32);
      l0 += rs;
#pragma unroll
      for (int j = 0; j < 4; ++j) {
        pa00[j] = (__bf16)p[0][j];
        pa00[4 + j] = (__bf16)p[1][j];
        pa01[j] = (__bf16)p[2][j];
        pa01[4 + j] = (__bf16)p[3][j];
      }
    }
    {
      float rs = 0.f;
      float p[4][4];
#pragma unroll
      for (int t = 0; t < 4; ++t)
#pragma unroll
        for (int j = 0; j < 4; ++j) {
          p[t][j] = __builtin_amdgcn_exp2f(st1[t][j] - m1);
          rs += p[t][j];
        }
      rs += __shfl_xor(rs, 16);
      rs += __shfl_xor(rs, 32);
      l1 += rs;
#pragma unroll
      for (int j = 0; j < 4; ++j) {
        pa10[j] = (__bf16)p[0][j];
        pa10[4 + j] = (__bf16)p[1][j];
        pa11[j] = (__bf16)p[2][j];
        pa11[4 + j] = (__bf16)p[3][j];
      }
    }

    __builtin_amdgcn_s_setprio(1);
#pragma unroll
    for (int n = 0; n < 4; ++n) {
      const int ro = (n * 16 + lq) * 64;
      bf16x8 v0 = *(const bf16x8*)(Vlc + ro + ckV0);
      bf16x8 v1 = *(const bf16x8*)(Vlc + ro + ckV1);
      on0[n] = __builtin_amdgcn_mfma_f32_16x16x32_bf16(pa00, v0, on0[n], 0, 0, 0);
      on0[n] = __builtin_amdgcn_mfma_f32_16x16x32_bf16(pa01, v1, on0[n], 0, 0, 0);
      on1[n] = __builtin_amdgcn_mfma_f32_16x16x32_bf16(pa10, v0, on1[n], 0, 0, 0);
      on1[n] = __builtin_amdgcn_mfma_f32_16x16x32_bf16(pa11, v1, on1[n], 0, 0, 0);
    }
    __builtin_amdgcn_s_setprio(0);

    asm volatile("s_waitcnt vmcnt(0)" ::: "memory");
    __syncthreads();
    cur ^= 1;
  }

  const int b = bh >> 4, h = bh & 15;
  {
    u16* Ob = Aout + (size_t)(b * 2048 + qbase + kg * 4) * 1024 + h * 64 + lq;
#pragma unroll
    for (int j = 0; j < 4; ++j) {
      float lj = __shfl(l0, kg * 4 + j);
      float inv = 1.f / lj;
#pragma unroll
      for (int n = 0; n < 4; ++n)
        Ob[(size_t)j * 1024 + n * 16] = f2bf(on0[n][j] * inv);
    }
  }
  {
    u16* Ob = Aout + (size_t)(b * 2048 + qbase + 16 + kg * 4) * 1024 + h * 64 + lq;
#pragma unroll
    for (int j = 0; j < 4; ++j) {
      float lj = __shfl(l1, kg * 4 + j);
      float inv = 1.f / lj;
#pragma unroll
      for (int n = 0; n < 4; ++n)
        Ob[(size_t)j * 1024 + n * 16] = f2bf(on1[n][j] * inv);
    }
  }
}

// ---------------- launch ----------------
extern "C" void kernel_launch(void* const* d_in, const int* in_sizes, int n_in,
                              void* d_out, int out_size, void* d_ws, size_t ws_size,
                              hipStream_t stream) {
  const float* query = (const float*)d_in[0];
  const float* Wqkv = (const float*)d_in[3];
  const float* bqkv = (const float*)d_in[4];
  const float* Wout = (const float*)d_in[5];
  const float* bout = (const float*)d_in[6];
  float* out = (float*)d_out;

  char* ws = (char*)d_ws;
  u16* qx = (u16*)(ws);                // 16 MiB: query bf16, reused as attn out
  u16* wqkvb = (u16*)(ws + 16777216);  // 6 MiB
  u16* woutb = (u16*)(ws + 23068672);  // 2 MiB
  u16* Qh = (u16*)(ws + 25165824);     // 16 MiB [B,H,S,64] (pre-scaled)
  u16* Kh = (u16*)(ws + 41943040);     // 16 MiB [B,H,S,64]
  u16* Vt = (u16*)(ws + 58720256);     // 16 MiB [B,H,64,S]
  u16* attn = qx;                      // reuse (qx dead after gemm_qkv)

  cvt_f32_bf16<<<4096, 256, 0, stream>>>(query, qx, 8388608 / 8);
  cvt_f32_bf16<<<1536, 256, 0, stream>>>(Wqkv, wqkvb, 3145728 / 8);
  cvt_f32_bf16<<<512, 256, 0, stream>>>(Wout, woutb, 1048576 / 8);

  gemm_qkv8<<<384, 512, 0, stream>>>(qx, wqkvb, bqkv, Qh, Kh, Vt);
  attn_kernel<<<1024, 256, 0, stream>>>(Qh, Kh, Vt, attn);
  gemm_out_k<<<512, 256, 0, stream>>>(attn, woutb, bout, out);
}